// Round 1
// baseline (751.201 us; speedup 1.0000x reference)
//
#include <hip/hip_runtime.h>
#include <math.h>

#define EMBED 768
#define NHEADS 12
#define HDIM 64
#define NBATCH 2
#define SEQ 2048
#define NTOK (NBATCH*SEQ)        // 4096
#define QKV_N (3*EMBED)          // 2304
#define SCALING 0.125f           // 64^-0.5

// ---------------------------------------------------------------------------
// QKV projection: C[n][j] = sum_k X[n][k]*Wqkv[j][k] + b[j], then scatter to
// Q (scaled), K, V buffers in [B][H][S][hd] layout.
// 64x64 tile, BK=16, 256 threads, 4x4 microtile per thread.
// ---------------------------------------------------------------------------
__global__ __launch_bounds__(256)
void qkv_proj_kernel(const float* __restrict__ X, const float* __restrict__ W,
                     const float* __restrict__ bias,
                     float* __restrict__ Qb, float* __restrict__ Kb,
                     float* __restrict__ Vb)
{
    __shared__ float As[16][68];   // [k][m], pad 68 keeps float4 alignment, 2-way banks (free)
    __shared__ float Bs[16][68];   // [k][n]
    const int m0 = blockIdx.x * 64;
    const int n0 = blockIdx.y * 64;
    const int tid = threadIdx.x;
    const int ty = tid >> 4, tx = tid & 15;
    const int rm = ty * 4, cn = tx * 4;
    const int lm = tid >> 2;            // 0..63 load row
    const int lk = (tid & 3) * 4;       // 0,4,8,12 load k-offset

    float acc[4][4] = {};

    for (int k0 = 0; k0 < EMBED; k0 += 16) {
        float4 xa = *(const float4*)&X[(size_t)(m0 + lm) * EMBED + k0 + lk];
        float4 wb = *(const float4*)&W[(size_t)(n0 + lm) * EMBED + k0 + lk];
        __syncthreads();
        As[lk+0][lm] = xa.x; As[lk+1][lm] = xa.y; As[lk+2][lm] = xa.z; As[lk+3][lm] = xa.w;
        Bs[lk+0][lm] = wb.x; Bs[lk+1][lm] = wb.y; Bs[lk+2][lm] = wb.z; Bs[lk+3][lm] = wb.w;
        __syncthreads();
        #pragma unroll
        for (int kk = 0; kk < 16; ++kk) {
            float4 a4 = *(const float4*)&As[kk][rm];
            float4 b4 = *(const float4*)&Bs[kk][cn];
            float a[4] = {a4.x, a4.y, a4.z, a4.w};
            float b[4] = {b4.x, b4.y, b4.z, b4.w};
            #pragma unroll
            for (int ii = 0; ii < 4; ++ii)
                #pragma unroll
                for (int jj = 0; jj < 4; ++jj)
                    acc[ii][jj] = fmaf(a[ii], b[jj], acc[ii][jj]);
        }
    }

    // n0 is 64-aligned and 64 | 768, so part p and head h are block-uniform.
    const int p = n0 / EMBED;               // 0=q,1=k,2=v
    const int h = (n0 % EMBED) / HDIM;      // head
    float* dst = (p == 0) ? Qb : (p == 1) ? Kb : Vb;
    const float mul = (p == 0) ? SCALING : 1.0f;
    #pragma unroll
    for (int ii = 0; ii < 4; ++ii) {
        int n = m0 + rm + ii;               // token
        int b = n / SEQ, s = n % SEQ;
        float4 v;
        v.x = (acc[ii][0] + bias[n0+cn+0]) * mul;
        v.y = (acc[ii][1] + bias[n0+cn+1]) * mul;
        v.z = (acc[ii][2] + bias[n0+cn+2]) * mul;
        v.w = (acc[ii][3] + bias[n0+cn+3]) * mul;
        *(float4*)&dst[(((size_t)b * NHEADS + h) * SEQ + s) * HDIM + cn] = v;
    }
}

// ---------------------------------------------------------------------------
// Flash attention, fp32. One block per (b,h, 64-row Q tile). Online softmax.
// LDS: Qs/KPs/Vs 64x68 fp32; KPs holds K^T during scores, then P^T for PV.
// 52 KB LDS -> 3 blocks/CU.
// ---------------------------------------------------------------------------
__global__ __launch_bounds__(256)
void attn_kernel(const float* __restrict__ Qb, const float* __restrict__ Kb,
                 const float* __restrict__ Vb, float* __restrict__ AO)
{
    __shared__ float Qs[64][68];   // [d][r]
    __shared__ float KPs[64][68];  // [d][c] as K^T, then [t][r] as P^T
    __shared__ float Vs[64][68];   // [t][d]

    const int qt = blockIdx.x;           // 0..31
    const int bh = blockIdx.y;           // 0..23
    const int b  = bh / NHEADS, h = bh % NHEADS;
    const int tid = threadIdx.x;
    const int ty = tid >> 4, tx = tid & 15;
    const int rm = ty * 4, cn = tx * 4;
    const int lr0 = tid >> 4;            // load row base (+16 steps)
    const int ld4 = (tid & 15) * 4;      // load d-offset

    const float* qptr  = Qb + ((size_t)bh * SEQ + qt * 64) * HDIM;
    const float* kbase = Kb + (size_t)bh * SEQ * HDIM;
    const float* vbase = Vb + (size_t)bh * SEQ * HDIM;

    // Load Q tile transposed: Qs[d][r]
    #pragma unroll
    for (int i = 0; i < 4; ++i) {
        int r = lr0 + 16 * i;
        float4 v = *(const float4*)&qptr[(size_t)r * HDIM + ld4];
        Qs[ld4+0][r] = v.x; Qs[ld4+1][r] = v.y; Qs[ld4+2][r] = v.z; Qs[ld4+3][r] = v.w;
    }

    float o[4][4] = {};
    float mrow[4] = {-1e30f, -1e30f, -1e30f, -1e30f};
    float lrow[4] = {};

    for (int kt = 0; kt < SEQ / 64; ++kt) {
        __syncthreads();   // prev PV readers done (and Qs visible on first iter)
        #pragma unroll
        for (int i = 0; i < 4; ++i) {
            int r = lr0 + 16 * i;
            float4 kv = *(const float4*)&kbase[(size_t)(kt * 64 + r) * HDIM + ld4];
            KPs[ld4+0][r] = kv.x; KPs[ld4+1][r] = kv.y; KPs[ld4+2][r] = kv.z; KPs[ld4+3][r] = kv.w;
            float4 vv = *(const float4*)&vbase[(size_t)(kt * 64 + r) * HDIM + ld4];
            *(float4*)&Vs[r][ld4] = vv;
        }
        __syncthreads();

        // Scores: s[r][c] = sum_d Qs[d][r]*K^T[d][c]
        float s[4][4] = {};
        #pragma unroll 8
        for (int d = 0; d < 64; ++d) {
            float4 a4 = *(const float4*)&Qs[d][rm];
            float4 b4 = *(const float4*)&KPs[d][cn];
            float a[4] = {a4.x, a4.y, a4.z, a4.w};
            float bb[4] = {b4.x, b4.y, b4.z, b4.w};
            #pragma unroll
            for (int ii = 0; ii < 4; ++ii)
                #pragma unroll
                for (int jj = 0; jj < 4; ++jj)
                    s[ii][jj] = fmaf(a[ii], bb[jj], s[ii][jj]);
        }

        // Online softmax update (row groups = 16 lanes sharing ty within a wave)
        #pragma unroll
        for (int ii = 0; ii < 4; ++ii) {
            float mx = fmaxf(fmaxf(s[ii][0], s[ii][1]), fmaxf(s[ii][2], s[ii][3]));
            mx = fmaxf(mx, __shfl_xor(mx, 1));
            mx = fmaxf(mx, __shfl_xor(mx, 2));
            mx = fmaxf(mx, __shfl_xor(mx, 4));
            mx = fmaxf(mx, __shfl_xor(mx, 8));
            float mnew = fmaxf(mrow[ii], mx);
            float corr = __expf(mrow[ii] - mnew);
            mrow[ii] = mnew;
            float rs = 0.f;
            #pragma unroll
            for (int jj = 0; jj < 4; ++jj) {
                float pv = __expf(s[ii][jj] - mnew);
                s[ii][jj] = pv;
                rs += pv;
            }
            rs += __shfl_xor(rs, 1);
            rs += __shfl_xor(rs, 2);
            rs += __shfl_xor(rs, 4);
            rs += __shfl_xor(rs, 8);
            lrow[ii] = lrow[ii] * corr + rs;
            o[ii][0] *= corr; o[ii][1] *= corr; o[ii][2] *= corr; o[ii][3] *= corr;
        }

        __syncthreads();   // everyone done reading K^T before overwriting with P^T
        // Write P^T: KPs[t][r]
        #pragma unroll
        for (int jj = 0; jj < 4; ++jj) {
            float4 pv = make_float4(s[0][jj], s[1][jj], s[2][jj], s[3][jj]);
            *(float4*)&KPs[cn + jj][rm] = pv;
        }
        __syncthreads();

        // PV: o[r][dv] += sum_t P^T[t][r] * V[t][dv]
        #pragma unroll 8
        for (int t = 0; t < 64; ++t) {
            float4 p4 = *(const float4*)&KPs[t][rm];
            float4 v4 = *(const float4*)&Vs[t][cn];
            float p[4] = {p4.x, p4.y, p4.z, p4.w};
            float v[4] = {v4.x, v4.y, v4.z, v4.w};
            #pragma unroll
            for (int ii = 0; ii < 4; ++ii)
                #pragma unroll
                for (int jj = 0; jj < 4; ++jj)
                    o[ii][jj] = fmaf(p[ii], v[jj], o[ii][jj]);
        }
    }

    // Epilogue: normalize and write AO in [B][S][E] layout
    #pragma unroll
    for (int ii = 0; ii < 4; ++ii) {
        float inv = 1.0f / lrow[ii];
        float4 v = make_float4(o[ii][0]*inv, o[ii][1]*inv, o[ii][2]*inv, o[ii][3]*inv);
        int s = qt * 64 + rm + ii;
        *(float4*)&AO[((size_t)(b * SEQ + s)) * EMBED + h * HDIM + cn] = v;
    }
}

// ---------------------------------------------------------------------------
// Output projection: out[n][j] = sum_k AO[n][k]*Wout[j][k] + bout[j]
// ---------------------------------------------------------------------------
__global__ __launch_bounds__(256)
void out_proj_kernel(const float* __restrict__ A, const float* __restrict__ W,
                     const float* __restrict__ bias, float* __restrict__ out)
{
    __shared__ float As[16][68];
    __shared__ float Bs[16][68];
    const int m0 = blockIdx.x * 64;
    const int n0 = blockIdx.y * 64;
    const int tid = threadIdx.x;
    const int ty = tid >> 4, tx = tid & 15;
    const int rm = ty * 4, cn = tx * 4;
    const int lm = tid >> 2;
    const int lk = (tid & 3) * 4;

    float acc[4][4] = {};

    for (int k0 = 0; k0 < EMBED; k0 += 16) {
        float4 xa = *(const float4*)&A[(size_t)(m0 + lm) * EMBED + k0 + lk];
        float4 wb = *(const float4*)&W[(size_t)(n0 + lm) * EMBED + k0 + lk];
        __syncthreads();
        As[lk+0][lm] = xa.x; As[lk+1][lm] = xa.y; As[lk+2][lm] = xa.z; As[lk+3][lm] = xa.w;
        Bs[lk+0][lm] = wb.x; Bs[lk+1][lm] = wb.y; Bs[lk+2][lm] = wb.z; Bs[lk+3][lm] = wb.w;
        __syncthreads();
        #pragma unroll
        for (int kk = 0; kk < 16; ++kk) {
            float4 a4 = *(const float4*)&As[kk][rm];
            float4 b4 = *(const float4*)&Bs[kk][cn];
            float a[4] = {a4.x, a4.y, a4.z, a4.w};
            float b[4] = {b4.x, b4.y, b4.z, b4.w};
            #pragma unroll
            for (int ii = 0; ii < 4; ++ii)
                #pragma unroll
                for (int jj = 0; jj < 4; ++jj)
                    acc[ii][jj] = fmaf(a[ii], b[jj], acc[ii][jj]);
        }
    }

    #pragma unroll
    for (int ii = 0; ii < 4; ++ii) {
        float4 v;
        v.x = acc[ii][0] + bias[n0+cn+0];
        v.y = acc[ii][1] + bias[n0+cn+1];
        v.z = acc[ii][2] + bias[n0+cn+2];
        v.w = acc[ii][3] + bias[n0+cn+3];
        *(float4*)&out[(size_t)(m0 + rm + ii) * EMBED + n0 + cn] = v;
    }
}

// ---------------------------------------------------------------------------
extern "C" void kernel_launch(void* const* d_in, const int* in_sizes, int n_in,
                              void* d_out, int out_size, void* d_ws, size_t ws_size,
                              hipStream_t stream)
{
    const float* x    = (const float*)d_in[0];   // (B,S,E)
    const float* wqkv = (const float*)d_in[1];   // (3E,E)
    const float* bqkv = (const float*)d_in[2];   // (3E,)
    const float* wout = (const float*)d_in[3];   // (E,E)
    const float* bout = (const float*)d_in[4];   // (E,)
    float* out = (float*)d_out;

    const size_t per = (size_t)NBATCH * NHEADS * SEQ * HDIM;  // 3,145,728 floats
    float* Qb = (float*)d_ws;
    float* Kb = Qb + per;
    float* Vb = Kb + per;
    float* AO = Vb + per;   // [B][S][E]

    dim3 g1(NTOK / 64, QKV_N / 64);     // (64, 36)
    qkv_proj_kernel<<<g1, 256, 0, stream>>>(x, wqkv, bqkv, Qb, Kb, Vb);

    dim3 g2(SEQ / 64, NBATCH * NHEADS); // (32, 24)
    attn_kernel<<<g2, 256, 0, stream>>>(Qb, Kb, Vb, AO);

    dim3 g3(NTOK / 64, EMBED / 64);     // (64, 12)
    out_proj_kernel<<<g3, 256, 0, stream>>>(AO, wout, bout, out);
}

// Round 2
// 314.669 us; speedup vs baseline: 2.3873x; 2.3873x over previous
//
#include <hip/hip_runtime.h>
#include <hip/hip_bf16.h>
#include <math.h>

typedef unsigned short u16;
typedef __attribute__((ext_vector_type(8))) short bf16x8;   // 8 bf16 = 4 VGPRs
typedef __attribute__((ext_vector_type(4))) float f32x4;

#define EMBED 768
#define NHEADS 12
#define HDIM 64
#define NBATCH 2
#define SEQ 2048
#define NTOK 4096
#define QKV_N 2304
#define SCALING 0.125f
#define LDT 40   // GEMM LDS row stride (elements): 80 B, 16B-aligned, spreads banks
#define LQ 72    // attn LDS row stride (elements): 144 B, 16B-aligned

__device__ __forceinline__ u16 f2b(float f) {
    __hip_bfloat16 h = __float2bfloat16(f);
    return __builtin_bit_cast(u16, h);
}

__device__ __forceinline__ f32x4 mfma16(bf16x8 a, bf16x8 b, f32x4 c) {
    return __builtin_amdgcn_mfma_f32_16x16x32_bf16(a, b, c, 0, 0, 0);
}

// ---------------------------------------------------------------------------
// fp32 -> bf16 cast for x, w_qkv, w_out (one fused kernel, 4 elems/thread)
// ---------------------------------------------------------------------------
__global__ __launch_bounds__(256)
void cast_kernel(const float* __restrict__ s0, u16* __restrict__ d0, int n0,
                 const float* __restrict__ s1, u16* __restrict__ d1, int n1,
                 const float* __restrict__ s2, u16* __restrict__ d2, int n2)
{
    int idx = (blockIdx.x * 256 + threadIdx.x) * 4;
    const float* s; u16* d; int i;
    if (idx < n0)            { s = s0; d = d0; i = idx; }
    else if (idx < n0 + n1)  { s = s1; d = d1; i = idx - n0; }
    else                     { s = s2; d = d2; i = idx - n0 - n1; if (i >= n2) return; }
    float4 v = *(const float4*)&s[i];
    ushort4 o;
    o.x = f2b(v.x); o.y = f2b(v.y); o.z = f2b(v.z); o.w = f2b(v.w);
    *(ushort4*)&d[i] = o;
}

// ---------------------------------------------------------------------------
// QKV projection, bf16 MFMA. C[m][n] = sum_k X[m][k]*W[n][k] (+bias, *scale).
// 128x128 tile, BK=32, 256 thr = 4 waves, each wave 64x64 (4x4 16x16x32 MFMAs).
// Epilogue scatters to Q(scaled)/K/V bf16 buffers [bh][s][d].
// ---------------------------------------------------------------------------
__global__ __launch_bounds__(256)
void qkv_gemm(const u16* __restrict__ A, const u16* __restrict__ W,
              const float* __restrict__ bias,
              u16* __restrict__ Qb, u16* __restrict__ Kb, u16* __restrict__ Vb)
{
    __shared__ __align__(16) u16 As[128 * LDT];
    __shared__ __align__(16) u16 Bs[128 * LDT];
    const int m0 = blockIdx.x * 128;
    const int n0 = blockIdx.y * 128;
    const int tid = threadIdx.x;
    const int w = tid >> 6, l = tid & 63;
    const int c = l & 15, q = l >> 4;
    const int wm = (w >> 1) * 64, wn = (w & 1) * 64;

    f32x4 acc[4][4] = {};

    for (int k0 = 0; k0 < EMBED; k0 += 32) {
        uint4 av[2], bv[2];
        #pragma unroll
        for (int i = 0; i < 2; ++i) {
            int ch = tid + i * 256;               // 512 chunks of 8 bf16
            int row = ch >> 2, c8 = (ch & 3) * 8;
            av[i] = *(const uint4*)&A[(size_t)(m0 + row) * EMBED + k0 + c8];
            bv[i] = *(const uint4*)&W[(size_t)(n0 + row) * EMBED + k0 + c8];
        }
        __syncthreads();
        #pragma unroll
        for (int i = 0; i < 2; ++i) {
            int ch = tid + i * 256;
            int row = ch >> 2, c8 = (ch & 3) * 8;
            *(uint4*)&As[row * LDT + c8] = av[i];
            *(uint4*)&Bs[row * LDT + c8] = bv[i];
        }
        __syncthreads();
        bf16x8 af[4], bf_[4];
        #pragma unroll
        for (int i = 0; i < 4; ++i)
            af[i] = *(const bf16x8*)&As[(wm + i * 16 + c) * LDT + q * 8];
        #pragma unroll
        for (int j = 0; j < 4; ++j)
            bf_[j] = *(const bf16x8*)&Bs[(wn + j * 16 + c) * LDT + q * 8];
        #pragma unroll
        for (int i = 0; i < 4; ++i)
            #pragma unroll
            for (int j = 0; j < 4; ++j)
                acc[i][j] = mfma16(af[i], bf_[j], acc[i][j]);
    }

    // epilogue: part p uniform per block (768 % 128 == 0)
    const int p = n0 / EMBED;
    u16* dst = (p == 0) ? Qb : (p == 1) ? Kb : Vb;
    const float mul = (p == 0) ? SCALING : 1.0f;
    const int ncol0 = n0 + wn;                    // 64-aligned
    const int h = (ncol0 % EMBED) / HDIM;         // wave-uniform head
    #pragma unroll
    for (int j = 0; j < 4; ++j) {
        int n = ncol0 + j * 16 + c;
        int d = j * 16 + c;                       // n % 64
        float bval = bias[n];
        #pragma unroll
        for (int i = 0; i < 4; ++i) {
            #pragma unroll
            for (int r = 0; r < 4; ++r) {
                int m = m0 + wm + i * 16 + q * 4 + r;   // token
                int b = m >> 11, s = m & (SEQ - 1);
                float v = (acc[i][j][r] + bval) * mul;
                dst[(((size_t)(b * NHEADS + h)) * SEQ + s) * HDIM + d] = f2b(v);
            }
        }
    }
}

// ---------------------------------------------------------------------------
// V [bh][s][d] -> VT [bh][d][s]  (LDS-tiled transpose, coalesced both sides)
// ---------------------------------------------------------------------------
__global__ __launch_bounds__(256)
void vtrans_kernel(const u16* __restrict__ Vb, u16* __restrict__ VT)
{
    __shared__ __align__(16) u16 T[64 * LQ];
    const int s0 = blockIdx.x * 64;
    const int bh = blockIdx.y;
    const int tid = threadIdx.x;
    #pragma unroll
    for (int i = 0; i < 2; ++i) {
        int ch = tid + i * 256;                  // 512 chunks
        int row = ch >> 3, d0 = (ch & 7) * 8;
        uint4 v = *(const uint4*)&Vb[((size_t)bh * SEQ + s0 + row) * HDIM + d0];
        u16 e[8]; *(uint4*)e = v;
        #pragma unroll
        for (int u = 0; u < 8; ++u) T[(d0 + u) * LQ + row] = e[u];
    }
    __syncthreads();
    #pragma unroll
    for (int i = 0; i < 2; ++i) {
        int ch = tid + i * 256;
        int d = ch >> 3, so = (ch & 7) * 8;
        uint4 v = *(const uint4*)&T[d * LQ + so];
        *(uint4*)&VT[((size_t)bh * HDIM + d) * SEQ + s0 + so] = v;
    }
}

// ---------------------------------------------------------------------------
// Flash attention, bf16 MFMA. Block = (64 Q-rows) x (b,h); 4 waves, wave w
// owns Q rows w*16..w*16+15. K-tiles of 64; online softmax in fp32; P goes
// through wave-private LDS to become the PV A-operand.
// ---------------------------------------------------------------------------
__global__ __launch_bounds__(256)
void attn_kernel(const u16* __restrict__ Qb, const u16* __restrict__ Kb,
                 const u16* __restrict__ VT, u16* __restrict__ AO)
{
    __shared__ __align__(16) u16 Qs[64 * LQ];
    __shared__ __align__(16) u16 Ks[64 * LQ];
    __shared__ __align__(16) u16 Vs[64 * LQ];    // V^T tile: [d][t]
    __shared__ __align__(16) u16 Ps[4][16 * LQ]; // wave-private P strips

    const int qt = blockIdx.x;
    const int bh = blockIdx.y;
    const int b = bh / NHEADS, h = bh % NHEADS;
    const int tid = threadIdx.x;
    const int w = tid >> 6, l = tid & 63;
    const int c = l & 15, q = l >> 4;

    const u16* qg = Qb + ((size_t)bh * SEQ + qt * 64) * HDIM;
    const u16* kg = Kb + (size_t)bh * SEQ * HDIM;
    const u16* vg = VT + (size_t)bh * HDIM * SEQ;

    #pragma unroll
    for (int i = 0; i < 2; ++i) {
        int ch = tid + i * 256;
        int row = ch >> 3, d0 = (ch & 7) * 8;
        *(uint4*)&Qs[row * LQ + d0] = *(const uint4*)&qg[row * HDIM + d0];
    }
    __syncthreads();
    bf16x8 aq0 = *(const bf16x8*)&Qs[(w * 16 + c) * LQ + q * 8];
    bf16x8 aq1 = *(const bf16x8*)&Qs[(w * 16 + c) * LQ + 32 + q * 8];

    f32x4 o[4] = {};
    float mrow[4] = {-1e30f, -1e30f, -1e30f, -1e30f};
    float lrow[4] = {};

    for (int kt = 0; kt < SEQ / 64; ++kt) {
        __syncthreads();   // previous iteration's LDS readers done
        #pragma unroll
        for (int i = 0; i < 2; ++i) {
            int ch = tid + i * 256;
            int row = ch >> 3, d0 = (ch & 7) * 8;
            *(uint4*)&Ks[row * LQ + d0] = *(const uint4*)&kg[(size_t)(kt * 64 + row) * HDIM + d0];
            *(uint4*)&Vs[row * LQ + d0] = *(const uint4*)&vg[(size_t)row * SEQ + kt * 64 + d0];
        }
        __syncthreads();

        // scores S = Q K^T  (wave: 16 rows x 64 keys)
        f32x4 sc[4];
        #pragma unroll
        for (int j = 0; j < 4; ++j) {
            bf16x8 bk0 = *(const bf16x8*)&Ks[(j * 16 + c) * LQ + q * 8];
            bf16x8 bk1 = *(const bf16x8*)&Ks[(j * 16 + c) * LQ + 32 + q * 8];
            f32x4 z = {};
            z = mfma16(aq0, bk0, z);
            sc[j] = mfma16(aq1, bk1, z);
        }

        // online softmax (row = q*4 + r, spread over the quad's 16 lanes)
        float corr[4];
        #pragma unroll
        for (int r = 0; r < 4; ++r) {
            float mx = fmaxf(fmaxf(sc[0][r], sc[1][r]), fmaxf(sc[2][r], sc[3][r]));
            mx = fmaxf(mx, __shfl_xor(mx, 1));
            mx = fmaxf(mx, __shfl_xor(mx, 2));
            mx = fmaxf(mx, __shfl_xor(mx, 4));
            mx = fmaxf(mx, __shfl_xor(mx, 8));
            float mnew = fmaxf(mrow[r], mx);
            corr[r] = __expf(mrow[r] - mnew);
            mrow[r] = mnew;
            float rs = 0.f;
            #pragma unroll
            for (int j = 0; j < 4; ++j) {
                float pv = __expf(sc[j][r] - mnew);
                sc[j][r] = pv;
                rs += pv;
            }
            rs += __shfl_xor(rs, 1);
            rs += __shfl_xor(rs, 2);
            rs += __shfl_xor(rs, 4);
            rs += __shfl_xor(rs, 8);
            lrow[r] = lrow[r] * corr[r] + rs;
        }

        // P (C-layout) -> wave-private LDS -> A-operand layout. No barrier:
        // same-wave DS ops are ordered; region is private to this wave.
        u16* ps = Ps[w];
        #pragma unroll
        for (int j = 0; j < 4; ++j)
            #pragma unroll
            for (int r = 0; r < 4; ++r)
                ps[(q * 4 + r) * LQ + j * 16 + c] = f2b(sc[j][r]);
        bf16x8 ap0 = *(const bf16x8*)&ps[c * LQ + q * 8];
        bf16x8 ap1 = *(const bf16x8*)&ps[c * LQ + 32 + q * 8];

        // O = corr*O + P V
        #pragma unroll
        for (int jd = 0; jd < 4; ++jd) {
            bf16x8 bv0 = *(const bf16x8*)&Vs[(jd * 16 + c) * LQ + q * 8];
            bf16x8 bv1 = *(const bf16x8*)&Vs[(jd * 16 + c) * LQ + 32 + q * 8];
            f32x4 t = o[jd];
            #pragma unroll
            for (int r = 0; r < 4; ++r) t[r] *= corr[r];
            t = mfma16(ap0, bv0, t);
            t = mfma16(ap1, bv1, t);
            o[jd] = t;
        }
    }

    // epilogue -> AO [token][EMBED] bf16
    float inv[4];
    #pragma unroll
    for (int r = 0; r < 4; ++r) inv[r] = 1.0f / lrow[r];
    #pragma unroll
    for (int jd = 0; jd < 4; ++jd) {
        #pragma unroll
        for (int r = 0; r < 4; ++r) {
            int s = qt * 64 + w * 16 + q * 4 + r;
            float v = o[jd][r] * inv[r];
            AO[((size_t)(b * SEQ + s)) * EMBED + h * HDIM + jd * 16 + c] = f2b(v);
        }
    }
}

// ---------------------------------------------------------------------------
// Output projection, bf16 MFMA -> fp32 out. Same 128x128 structure.
// ---------------------------------------------------------------------------
__global__ __launch_bounds__(256)
void out_gemm(const u16* __restrict__ A, const u16* __restrict__ W,
              const float* __restrict__ bias, float* __restrict__ out)
{
    __shared__ __align__(16) u16 As[128 * LDT];
    __shared__ __align__(16) u16 Bs[128 * LDT];
    const int m0 = blockIdx.x * 128;
    const int n0 = blockIdx.y * 128;
    const int tid = threadIdx.x;
    const int w = tid >> 6, l = tid & 63;
    const int c = l & 15, q = l >> 4;
    const int wm = (w >> 1) * 64, wn = (w & 1) * 64;

    f32x4 acc[4][4] = {};

    for (int k0 = 0; k0 < EMBED; k0 += 32) {
        uint4 av[2], bv[2];
        #pragma unroll
        for (int i = 0; i < 2; ++i) {
            int ch = tid + i * 256;
            int row = ch >> 2, c8 = (ch & 3) * 8;
            av[i] = *(const uint4*)&A[(size_t)(m0 + row) * EMBED + k0 + c8];
            bv[i] = *(const uint4*)&W[(size_t)(n0 + row) * EMBED + k0 + c8];
        }
        __syncthreads();
        #pragma unroll
        for (int i = 0; i < 2; ++i) {
            int ch = tid + i * 256;
            int row = ch >> 2, c8 = (ch & 3) * 8;
            *(uint4*)&As[row * LDT + c8] = av[i];
            *(uint4*)&Bs[row * LDT + c8] = bv[i];
        }
        __syncthreads();
        bf16x8 af[4], bf_[4];
        #pragma unroll
        for (int i = 0; i < 4; ++i)
            af[i] = *(const bf16x8*)&As[(wm + i * 16 + c) * LDT + q * 8];
        #pragma unroll
        for (int j = 0; j < 4; ++j)
            bf_[j] = *(const bf16x8*)&Bs[(wn + j * 16 + c) * LDT + q * 8];
        #pragma unroll
        for (int i = 0; i < 4; ++i)
            #pragma unroll
            for (int j = 0; j < 4; ++j)
                acc[i][j] = mfma16(af[i], bf_[j], acc[i][j]);
    }

    #pragma unroll
    for (int j = 0; j < 4; ++j) {
        int n = n0 + wn + j * 16 + c;
        float bval = bias[n];
        #pragma unroll
        for (int i = 0; i < 4; ++i) {
            #pragma unroll
            for (int r = 0; r < 4; ++r) {
                int m = m0 + wm + i * 16 + q * 4 + r;
                out[(size_t)m * EMBED + n] = acc[i][j][r] + bval;
            }
        }
    }
}

// ---------------------------------------------------------------------------
extern "C" void kernel_launch(void* const* d_in, const int* in_sizes, int n_in,
                              void* d_out, int out_size, void* d_ws, size_t ws_size,
                              hipStream_t stream)
{
    const float* x    = (const float*)d_in[0];
    const float* wqkv = (const float*)d_in[1];
    const float* bqkv = (const float*)d_in[2];
    const float* wout = (const float*)d_in[3];
    const float* bout = (const float*)d_in[4];
    float* out = (float*)d_out;

    const int nx = NTOK * EMBED;          // 3,145,728
    const int nwq = QKV_N * EMBED;        // 1,769,472
    const int nwo = EMBED * EMBED;        //   589,824
    const size_t per = (size_t)NBATCH * NHEADS * SEQ * HDIM;  // 3,145,728

    u16* xb    = (u16*)d_ws;
    u16* wqkvb = xb + nx;
    u16* woutb = wqkvb + nwq;
    u16* Qb    = woutb + nwo;
    u16* Kb    = Qb + per;
    u16* Vb    = Kb + per;
    u16* VTb   = Vb + per;
    u16* AO    = VTb + per;

    int castTot = (nx + nwq + nwo) / 4;   // 1,376,256 threads
    cast_kernel<<<castTot / 256, 256, 0, stream>>>(x, xb, nx, wqkv, wqkvb, nwq, wout, woutb, nwo);

    dim3 g1(NTOK / 128, QKV_N / 128);     // (32, 18)
    qkv_gemm<<<g1, 256, 0, stream>>>(xb, wqkvb, bqkv, Qb, Kb, Vb);

    dim3 gt(SEQ / 64, NBATCH * NHEADS);   // (32, 24)
    vtrans_kernel<<<gt, 256, 0, stream>>>(Vb, VTb);

    dim3 g2(SEQ / 64, NBATCH * NHEADS);   // (32, 24)
    attn_kernel<<<g2, 256, 0, stream>>>(Qb, Kb, VTb, AO);

    dim3 g3(NTOK / 128, EMBED / 128);     // (32, 6)
    out_gemm<<<g3, 256, 0, stream>>>(AO, woutb, bout, out);
}

// Round 3
// 310.735 us; speedup vs baseline: 2.4175x; 1.0127x over previous
//
#include <hip/hip_runtime.h>
#include <hip/hip_bf16.h>
#include <math.h>

typedef unsigned short u16;
typedef unsigned int u32;
typedef __attribute__((ext_vector_type(8))) short bf16x8;   // 8 bf16 = 4 VGPRs
typedef __attribute__((ext_vector_type(4))) float f32x4;

#define EMBED 768
#define NHEADS 12
#define HDIM 64
#define NBATCH 2
#define SEQ 2048
#define NTOK 4096
#define QKV_N 2304
#define SCALING 0.125f
#define LDT 40   // GEMM LDS row stride (elements); (40*2B)%128B spreads banks
#define LQ 72    // attn LDS row stride; stride 36 words == 4 mod 32 -> conflict-free frags

__device__ __forceinline__ u16 f2b(float f) {
    __hip_bfloat16 h = __float2bfloat16(f);
    return __builtin_bit_cast(u16, h);
}
__device__ __forceinline__ u32 pk2(float a, float b) {
    return (u32)f2b(a) | ((u32)f2b(b) << 16);
}
__device__ __forceinline__ f32x4 mfma16(bf16x8 a, bf16x8 b, f32x4 c) {
    return __builtin_amdgcn_mfma_f32_16x16x32_bf16(a, b, c, 0, 0, 0);
}

// ---------------------------------------------------------------------------
// fp32 -> bf16 cast for x, w_qkv, w_out
// ---------------------------------------------------------------------------
__global__ __launch_bounds__(256)
void cast_kernel(const float* __restrict__ s0, u16* __restrict__ d0, int n0,
                 const float* __restrict__ s1, u16* __restrict__ d1, int n1,
                 const float* __restrict__ s2, u16* __restrict__ d2, int n2)
{
    int idx = (blockIdx.x * 256 + threadIdx.x) * 4;
    const float* s; u16* d; int i;
    if (idx < n0)            { s = s0; d = d0; i = idx; }
    else if (idx < n0 + n1)  { s = s1; d = d1; i = idx - n0; }
    else                     { s = s2; d = d2; i = idx - n0 - n1; if (i >= n2) return; }
    float4 v = *(const float4*)&s[i];
    ushort4 o;
    o.x = f2b(v.x); o.y = f2b(v.y); o.z = f2b(v.z); o.w = f2b(v.w);
    *(ushort4*)&d[i] = o;
}

// ---------------------------------------------------------------------------
// QKV projection, bf16 MFMA, double-buffered LDS (1 barrier/iter).
// 128x128 tile, BK=32, 4 waves each 64x64. Epilogue scatters Q*scale/K/V.
// ---------------------------------------------------------------------------
__global__ __launch_bounds__(256)
void qkv_gemm(const u16* __restrict__ A, const u16* __restrict__ W,
              const float* __restrict__ bias,
              u16* __restrict__ Qb, u16* __restrict__ Kb, u16* __restrict__ Vb)
{
    __shared__ __align__(16) u16 As[2][128 * LDT];
    __shared__ __align__(16) u16 Bs[2][128 * LDT];
    const int m0 = blockIdx.x * 128;
    const int n0 = blockIdx.y * 128;
    const int tid = threadIdx.x;
    const int w = tid >> 6, l = tid & 63;
    const int c = l & 15, q = l >> 4;
    const int wm = (w >> 1) * 64, wn = (w & 1) * 64;
    const int srow = tid >> 2, sc8 = (tid & 3) * 8;

    // prologue: stage k0=0 tile into buffer 0
    #pragma unroll
    for (int i = 0; i < 2; ++i) {
        int r = srow + i * 64;
        *(uint4*)&As[0][r * LDT + sc8] = *(const uint4*)&A[(size_t)(m0 + r) * EMBED + sc8];
        *(uint4*)&Bs[0][r * LDT + sc8] = *(const uint4*)&W[(size_t)(n0 + r) * EMBED + sc8];
    }

    f32x4 acc[4][4] = {};
    const int NK = EMBED / 32;   // 24

    #pragma unroll 2
    for (int kt = 0; kt < NK; ++kt) {
        const int cur = kt & 1;
        uint4 av[2], bv[2];
        if (kt + 1 < NK) {
            int k0 = (kt + 1) * 32;
            #pragma unroll
            for (int i = 0; i < 2; ++i) {
                int r = srow + i * 64;
                av[i] = *(const uint4*)&A[(size_t)(m0 + r) * EMBED + k0 + sc8];
                bv[i] = *(const uint4*)&W[(size_t)(n0 + r) * EMBED + k0 + sc8];
            }
        }
        __syncthreads();
        bf16x8 af[4], bf_[4];
        #pragma unroll
        for (int i = 0; i < 4; ++i)
            af[i] = *(const bf16x8*)&As[cur][(wm + i * 16 + c) * LDT + q * 8];
        #pragma unroll
        for (int j = 0; j < 4; ++j)
            bf_[j] = *(const bf16x8*)&Bs[cur][(wn + j * 16 + c) * LDT + q * 8];
        #pragma unroll
        for (int i = 0; i < 4; ++i)
            #pragma unroll
            for (int j = 0; j < 4; ++j)
                acc[i][j] = mfma16(af[i], bf_[j], acc[i][j]);
        if (kt + 1 < NK) {
            #pragma unroll
            for (int i = 0; i < 2; ++i) {
                int r = srow + i * 64;
                *(uint4*)&As[cur ^ 1][r * LDT + sc8] = av[i];
                *(uint4*)&Bs[cur ^ 1][r * LDT + sc8] = bv[i];
            }
        }
    }

    const int p = n0 / EMBED;
    u16* dst = (p == 0) ? Qb : (p == 1) ? Kb : Vb;
    const float mul = (p == 0) ? SCALING : 1.0f;
    const int ncol0 = n0 + wn;
    const int h = (ncol0 % EMBED) / HDIM;
    #pragma unroll
    for (int j = 0; j < 4; ++j) {
        int n = ncol0 + j * 16 + c;
        int d = j * 16 + c;
        float bval = bias[n];
        #pragma unroll
        for (int i = 0; i < 4; ++i) {
            #pragma unroll
            for (int r = 0; r < 4; ++r) {
                int m = m0 + wm + i * 16 + q * 4 + r;
                int b = m >> 11, s = m & (SEQ - 1);
                float v = (acc[i][j][r] + bval) * mul;
                dst[(((size_t)(b * NHEADS + h)) * SEQ + s) * HDIM + d] = f2b(v);
            }
        }
    }
}

// ---------------------------------------------------------------------------
// V [bh][s][d] -> VT [bh][d][s]
// ---------------------------------------------------------------------------
__global__ __launch_bounds__(256)
void vtrans_kernel(const u16* __restrict__ Vb, u16* __restrict__ VT)
{
    __shared__ __align__(16) u16 T[64 * LQ];
    const int s0 = blockIdx.x * 64;
    const int bh = blockIdx.y;
    const int tid = threadIdx.x;
    #pragma unroll
    for (int i = 0; i < 2; ++i) {
        int ch = tid + i * 256;
        int row = ch >> 3, d0 = (ch & 7) * 8;
        uint4 v = *(const uint4*)&Vb[((size_t)bh * SEQ + s0 + row) * HDIM + d0];
        u16 e[8]; *(uint4*)e = v;
        #pragma unroll
        for (int u = 0; u < 8; ++u) T[(d0 + u) * LQ + row] = e[u];
    }
    __syncthreads();
    #pragma unroll
    for (int i = 0; i < 2; ++i) {
        int ch = tid + i * 256;
        int d = ch >> 3, so = (ch & 7) * 8;
        uint4 v = *(const uint4*)&T[d * LQ + so];
        *(uint4*)&VT[((size_t)bh * HDIM + d) * SEQ + s0 + so] = v;
    }
}

// ---------------------------------------------------------------------------
// Flash attention, S^T formulation:
//   S^T = K·Q^T  (C-layout col = Q-row -> lane-local softmax, 2 shfls)
//   O^T = V^T·P^T (B-frag of P^T == A-frag of P: 4x ds_write_b64 + 2x b128)
// Double-buffered K/V (prefetch 1 tile ahead), one barrier per iteration.
// Q-tile LDS is reused as per-wave P strips after Q frags move to registers.
// ---------------------------------------------------------------------------
__global__ __launch_bounds__(256)
void attn_kernel(const u16* __restrict__ Qb, const u16* __restrict__ Kb,
                 const u16* __restrict__ VT, u16* __restrict__ AO)
{
    __shared__ __align__(16) u16 QPs[64 * LQ];     // Q tile, then P strips (wave w: rows w*16..)
    __shared__ __align__(16) u16 Ks[2][64 * LQ];   // K tile [t][d]
    __shared__ __align__(16) u16 Vs[2][64 * LQ];   // V^T tile [d][t]

    const int qt = blockIdx.x;
    const int bh = blockIdx.y;
    const int b = bh / NHEADS, h = bh % NHEADS;
    const int tid = threadIdx.x;
    const int w = tid >> 6, l = tid & 63;
    const int c = l & 15, q = l >> 4;
    const int lr = tid >> 3;          // 0..31 staging row
    const int ld = (tid & 7) * 8;     // 0..56 staging col

    const u16* qg = Qb + ((size_t)bh * SEQ + qt * 64) * HDIM;
    const u16* kg = Kb + (size_t)bh * SEQ * HDIM;
    const u16* vg = VT + (size_t)bh * HDIM * SEQ;

    // stage Q + K/V tile 0
    #pragma unroll
    for (int i = 0; i < 2; ++i) {
        int r = lr + i * 32;
        *(uint4*)&QPs[r * LQ + ld]   = *(const uint4*)&qg[(size_t)r * HDIM + ld];
        *(uint4*)&Ks[0][r * LQ + ld] = *(const uint4*)&kg[(size_t)r * HDIM + ld];
        *(uint4*)&Vs[0][r * LQ + ld] = *(const uint4*)&vg[(size_t)r * SEQ + ld];
    }
    __syncthreads();

    // Q^T B-fragments for this wave's 16 rows (registers for the whole loop)
    bf16x8 bq0 = *(const bf16x8*)&QPs[(w * 16 + c) * LQ + q * 8];
    bf16x8 bq1 = *(const bf16x8*)&QPs[(w * 16 + c) * LQ + 32 + q * 8];
    u16* ps = QPs + w * 16 * LQ;   // wave-private P strip (same rows as our Q rows)

    f32x4 o[4] = {};               // O^T: d = db*16+4q+r, row = c
    float mrow = -1e30f, lrow = 0.f;   // per-lane row = w*16 + c

    const int NT = SEQ / 64;   // 32
    #pragma unroll 2
    for (int kt = 0; kt < NT; ++kt) {
        const int cur = kt & 1;
        uint4 kv[2], vv[2];
        if (kt + 1 < NT) {
            #pragma unroll
            for (int i = 0; i < 2; ++i) {
                int r = lr + i * 32;
                kv[i] = *(const uint4*)&kg[(size_t)((kt + 1) * 64 + r) * HDIM + ld];
                vv[i] = *(const uint4*)&vg[(size_t)r * SEQ + (kt + 1) * 64 + ld];
            }
        }

        // S^T[key][row]: A = K (keys x d), B = Q^T (d x rows)
        f32x4 sc[4];
        #pragma unroll
        for (int kb = 0; kb < 4; ++kb) {
            bf16x8 ak0 = *(const bf16x8*)&Ks[cur][(kb * 16 + c) * LQ + q * 8];
            bf16x8 ak1 = *(const bf16x8*)&Ks[cur][(kb * 16 + c) * LQ + 32 + q * 8];
            f32x4 z = {};
            z = mfma16(ak0, bq0, z);
            sc[kb] = mfma16(ak1, bq1, z);
        }

        // online softmax for row c: 16 in-lane values + 2 cross-q shfls
        float m01 = fmaxf(fmaxf(sc[0][0], sc[0][1]), fmaxf(sc[0][2], sc[0][3]));
        float m23 = fmaxf(fmaxf(sc[1][0], sc[1][1]), fmaxf(sc[1][2], sc[1][3]));
        float m45 = fmaxf(fmaxf(sc[2][0], sc[2][1]), fmaxf(sc[2][2], sc[2][3]));
        float m67 = fmaxf(fmaxf(sc[3][0], sc[3][1]), fmaxf(sc[3][2], sc[3][3]));
        float tm = fmaxf(fmaxf(m01, m23), fmaxf(m45, m67));
        tm = fmaxf(tm, __shfl_xor(tm, 16));
        tm = fmaxf(tm, __shfl_xor(tm, 32));
        float mnew = fmaxf(mrow, tm);
        float corr = __expf(mrow - mnew);
        float rs = 0.f;
        #pragma unroll
        for (int kb = 0; kb < 4; ++kb)
            #pragma unroll
            for (int r = 0; r < 4; ++r) {
                float p = __expf(sc[kb][r] - mnew);
                sc[kb][r] = p;
                rs += p;
            }
        rs += __shfl_xor(rs, 16);
        rs += __shfl_xor(rs, 32);
        lrow = lrow * corr + rs;
        mrow = mnew;

        // P strip: row-major [row c][key], 4 consecutive keys per b64 write
        #pragma unroll
        for (int kb = 0; kb < 4; ++kb) {
            uint2 pr;
            pr.x = pk2(sc[kb][0], sc[kb][1]);
            pr.y = pk2(sc[kb][2], sc[kb][3]);
            *(uint2*)&ps[c * LQ + kb * 16 + q * 4] = pr;
        }
        // P^T B-fragments (== A-frag read pattern of P)
        bf16x8 bp0 = *(const bf16x8*)&ps[c * LQ + q * 8];
        bf16x8 bp1 = *(const bf16x8*)&ps[c * LQ + 32 + q * 8];

        // O^T = corr*O^T + V^T·P^T
        #pragma unroll
        for (int db = 0; db < 4; ++db) {
            bf16x8 av0 = *(const bf16x8*)&Vs[cur][(db * 16 + c) * LQ + q * 8];
            bf16x8 av1 = *(const bf16x8*)&Vs[cur][(db * 16 + c) * LQ + 32 + q * 8];
            f32x4 t = o[db] * corr;
            t = mfma16(av0, bp0, t);
            t = mfma16(av1, bp1, t);
            o[db] = t;
        }

        if (kt + 1 < NT) {
            #pragma unroll
            for (int i = 0; i < 2; ++i) {
                int r = lr + i * 32;
                *(uint4*)&Ks[cur ^ 1][r * LQ + ld] = kv[i];
                *(uint4*)&Vs[cur ^ 1][r * LQ + ld] = vv[i];
            }
            __syncthreads();
        }
    }

    // epilogue: lane (c,q) holds O^T[d=db*16+4q+r][row c]; pack pairs -> u32
    float inv = 1.0f / lrow;
    int s = qt * 64 + w * 16 + c;
    u32* aorow = (u32*)(AO + ((size_t)(b * SEQ + s)) * EMBED + h * HDIM);
    #pragma unroll
    for (int db = 0; db < 4; ++db) {
        aorow[db * 8 + q * 2 + 0] = pk2(o[db][0] * inv, o[db][1] * inv);
        aorow[db * 8 + q * 2 + 1] = pk2(o[db][2] * inv, o[db][3] * inv);
    }
}

// ---------------------------------------------------------------------------
// Output projection, 128x64 tile (384 blocks), double-buffered.
// Wave w: M-strip [w*32, w*32+32), all 64 N.
// ---------------------------------------------------------------------------
__global__ __launch_bounds__(256)
void out_gemm(const u16* __restrict__ A, const u16* __restrict__ W,
              const float* __restrict__ bias, float* __restrict__ out)
{
    __shared__ __align__(16) u16 As[2][128 * LDT];
    __shared__ __align__(16) u16 Bs[2][64 * LDT];
    const int m0 = blockIdx.x * 128;
    const int n0 = blockIdx.y * 64;
    const int tid = threadIdx.x;
    const int w = tid >> 6, l = tid & 63;
    const int c = l & 15, q = l >> 4;
    const int wm = w * 32;
    const int srow = tid >> 2, sc8 = (tid & 3) * 8;

    #pragma unroll
    for (int i = 0; i < 2; ++i) {
        int r = srow + i * 64;
        *(uint4*)&As[0][r * LDT + sc8] = *(const uint4*)&A[(size_t)(m0 + r) * EMBED + sc8];
    }
    *(uint4*)&Bs[0][srow * LDT + sc8] = *(const uint4*)&W[(size_t)(n0 + srow) * EMBED + sc8];

    f32x4 acc[2][4] = {};
    const int NK = EMBED / 32;   // 24

    #pragma unroll 2
    for (int kt = 0; kt < NK; ++kt) {
        const int cur = kt & 1;
        uint4 av[2], bv;
        if (kt + 1 < NK) {
            int k0 = (kt + 1) * 32;
            #pragma unroll
            for (int i = 0; i < 2; ++i) {
                int r = srow + i * 64;
                av[i] = *(const uint4*)&A[(size_t)(m0 + r) * EMBED + k0 + sc8];
            }
            bv = *(const uint4*)&W[(size_t)(n0 + srow) * EMBED + k0 + sc8];
        }
        __syncthreads();
        bf16x8 af[2], bf_[4];
        #pragma unroll
        for (int i = 0; i < 2; ++i)
            af[i] = *(const bf16x8*)&As[cur][(wm + i * 16 + c) * LDT + q * 8];
        #pragma unroll
        for (int j = 0; j < 4; ++j)
            bf_[j] = *(const bf16x8*)&Bs[cur][(j * 16 + c) * LDT + q * 8];
        #pragma unroll
        for (int i = 0; i < 2; ++i)
            #pragma unroll
            for (int j = 0; j < 4; ++j)
                acc[i][j] = mfma16(af[i], bf_[j], acc[i][j]);
        if (kt + 1 < NK) {
            #pragma unroll
            for (int i = 0; i < 2; ++i) {
                int r = srow + i * 64;
                *(uint4*)&As[cur ^ 1][r * LDT + sc8] = av[i];
            }
            *(uint4*)&Bs[cur ^ 1][srow * LDT + sc8] = bv;
        }
    }

    #pragma unroll
    for (int j = 0; j < 4; ++j) {
        int n = n0 + j * 16 + c;
        float bval = bias[n];
        #pragma unroll
        for (int i = 0; i < 2; ++i) {
            #pragma unroll
            for (int r = 0; r < 4; ++r) {
                int m = m0 + wm + i * 16 + q * 4 + r;
                out[(size_t)m * EMBED + n] = acc[i][j][r] + bval;
            }
        }
    }
}

// ---------------------------------------------------------------------------
extern "C" void kernel_launch(void* const* d_in, const int* in_sizes, int n_in,
                              void* d_out, int out_size, void* d_ws, size_t ws_size,
                              hipStream_t stream)
{
    const float* x    = (const float*)d_in[0];
    const float* wqkv = (const float*)d_in[1];
    const float* bqkv = (const float*)d_in[2];
    const float* wout = (const float*)d_in[3];
    const float* bout = (const float*)d_in[4];
    float* out = (float*)d_out;

    const int nx = NTOK * EMBED;
    const int nwq = QKV_N * EMBED;
    const int nwo = EMBED * EMBED;
    const size_t per = (size_t)NBATCH * NHEADS * SEQ * HDIM;

    u16* xb    = (u16*)d_ws;
    u16* wqkvb = xb + nx;
    u16* woutb = wqkvb + nwq;
    u16* Qb    = woutb + nwo;
    u16* Kb    = Qb + per;
    u16* Vb    = Kb + per;
    u16* VTb   = Vb + per;
    u16* AO    = VTb + per;

    int castTot = (nx + nwq + nwo) / 4;
    cast_kernel<<<castTot / 256, 256, 0, stream>>>(x, xb, nx, wqkv, wqkvb, nwq, wout, woutb, nwo);

    dim3 g1(NTOK / 128, QKV_N / 128);     // (32, 18)
    qkv_gemm<<<g1, 256, 0, stream>>>(xb, wqkvb, bqkv, Qb, Kb, Vb);

    dim3 gt(SEQ / 64, NBATCH * NHEADS);   // (32, 24)
    vtrans_kernel<<<gt, 256, 0, stream>>>(Vb, VTb);

    dim3 g2(SEQ / 64, NBATCH * NHEADS);   // (32, 24)
    attn_kernel<<<g2, 256, 0, stream>>>(Qb, Kb, VTb, AO);

    dim3 g3(NTOK / 128, EMBED / 64);      // (32, 12)
    out_gemm<<<g3, 256, 0, stream>>>(AO, woutb, bout, out);
}

// Round 4
// 279.913 us; speedup vs baseline: 2.6837x; 1.1101x over previous
//
#include <hip/hip_runtime.h>
#include <hip/hip_bf16.h>
#include <math.h>

typedef unsigned short u16;
typedef unsigned int u32;
typedef __attribute__((ext_vector_type(8))) short bf16x8;   // 8 bf16 = 4 VGPRs
typedef __attribute__((ext_vector_type(4))) float f32x4;

#define EMBED 768
#define NHEADS 12
#define HDIM 64
#define NBATCH 2
#define SEQ 2048
#define NTOK 4096
#define QKV_N 2304
#define BHTOT 24        // NBATCH*NHEADS
#define SCALING 0.125f
#define LDT 40          // GEMM LDS row stride (elements)
#define LQ 72           // attn LDS row stride (elements), 144 B (16B-aligned)
#define LT 72           // V-transpose scratch stride

__device__ __forceinline__ u16 f2b(float f) {
    __hip_bfloat16 h = __float2bfloat16(f);
    return __builtin_bit_cast(u16, h);
}
__device__ __forceinline__ u32 pk2(float a, float b) {
    return (u32)f2b(a) | ((u32)f2b(b) << 16);
}
__device__ __forceinline__ f32x4 mfma16(bf16x8 a, bf16x8 b, f32x4 c) {
    return __builtin_amdgcn_mfma_f32_16x16x32_bf16(a, b, c, 0, 0, 0);
}

// ---------------------------------------------------------------------------
// fp32 -> bf16 cast for the two weight matrices only (x is converted on the
// fly inside qkv_gemm staging).
// ---------------------------------------------------------------------------
__global__ __launch_bounds__(256)
void cast_w(const float* __restrict__ s1, u16* __restrict__ d1, int n1,
            const float* __restrict__ s2, u16* __restrict__ d2, int n2)
{
    int idx = (blockIdx.x * 256 + threadIdx.x) * 4;
    const float* s; u16* d; int i;
    if (idx < n1) { s = s1; d = d1; i = idx; }
    else          { s = s2; d = d2; i = idx - n1; if (i >= n2) return; }
    float4 v = *(const float4*)&s[i];
    ushort4 o;
    o.x = f2b(v.x); o.y = f2b(v.y); o.z = f2b(v.z); o.w = f2b(v.w);
    *(ushort4*)&d[i] = o;
}

// ---------------------------------------------------------------------------
// QKV projection. Reads x as fp32 (converts during staging), W as bf16.
// 128x128 tile, BK=32, double-buffered, 4 waves each 64x64.
// Epilogue: Q (*scale) and K scatter to [bh][s][d]; V is transposed through
// reused LDS and written as V^T [bh][d][s] (kills the vtrans kernel).
// ---------------------------------------------------------------------------
__global__ __launch_bounds__(256)
void qkv_gemm(const float* __restrict__ X, const u16* __restrict__ W,
              const float* __restrict__ bias,
              u16* __restrict__ Qb, u16* __restrict__ Kb, u16* __restrict__ VT)
{
    __shared__ __align__(16) u16 smem[4 * 128 * LDT];   // As[2]|Bs[2]; reused as T[4][64*LT]
    u16* As = smem;
    u16* Bs = smem + 2 * 128 * LDT;
    const int m0 = blockIdx.x * 128;
    const int n0 = blockIdx.y * 128;
    const int tid = threadIdx.x;
    const int w = tid >> 6, l = tid & 63;
    const int c = l & 15, q = l >> 4;
    const int wm = (w >> 1) * 64, wn = (w & 1) * 64;
    const int srow = tid >> 2, sc8 = (tid & 3) * 8;

    // prologue: stage k0=0 into buffer 0
    #pragma unroll
    for (int i = 0; i < 2; ++i) {
        int r = srow + i * 64;
        const float* xp = &X[(size_t)(m0 + r) * EMBED + sc8];
        float4 a0 = *(const float4*)xp;
        float4 a1 = *(const float4*)(xp + 4);
        uint4 pa = { pk2(a0.x, a0.y), pk2(a0.z, a0.w), pk2(a1.x, a1.y), pk2(a1.z, a1.w) };
        *(uint4*)&As[r * LDT + sc8] = pa;
        *(uint4*)&Bs[r * LDT + sc8] = *(const uint4*)&W[(size_t)(n0 + r) * EMBED + sc8];
    }

    f32x4 acc[4][4] = {};
    const int NK = EMBED / 32;   // 24

    #pragma unroll 2
    for (int kt = 0; kt < NK; ++kt) {
        const int cur = kt & 1;
        float4 ax[2][2]; uint4 bv[2];
        if (kt + 1 < NK) {
            int k0 = (kt + 1) * 32;
            #pragma unroll
            for (int i = 0; i < 2; ++i) {
                int r = srow + i * 64;
                const float* xp = &X[(size_t)(m0 + r) * EMBED + k0 + sc8];
                ax[i][0] = *(const float4*)xp;
                ax[i][1] = *(const float4*)(xp + 4);
                bv[i] = *(const uint4*)&W[(size_t)(n0 + r) * EMBED + k0 + sc8];
            }
        }
        __syncthreads();
        const u16* Ab = As + cur * 128 * LDT;
        const u16* Bb = Bs + cur * 128 * LDT;
        bf16x8 af[4], bf_[4];
        #pragma unroll
        for (int i = 0; i < 4; ++i)
            af[i] = *(const bf16x8*)&Ab[(wm + i * 16 + c) * LDT + q * 8];
        #pragma unroll
        for (int j = 0; j < 4; ++j)
            bf_[j] = *(const bf16x8*)&Bb[(wn + j * 16 + c) * LDT + q * 8];
        #pragma unroll
        for (int i = 0; i < 4; ++i)
            #pragma unroll
            for (int j = 0; j < 4; ++j)
                acc[i][j] = mfma16(af[i], bf_[j], acc[i][j]);
        if (kt + 1 < NK) {
            u16* An = As + (cur ^ 1) * 128 * LDT;
            u16* Bn = Bs + (cur ^ 1) * 128 * LDT;
            #pragma unroll
            for (int i = 0; i < 2; ++i) {
                int r = srow + i * 64;
                uint4 pa = { pk2(ax[i][0].x, ax[i][0].y), pk2(ax[i][0].z, ax[i][0].w),
                             pk2(ax[i][1].x, ax[i][1].y), pk2(ax[i][1].z, ax[i][1].w) };
                *(uint4*)&An[r * LDT + sc8] = pa;
                *(uint4*)&Bn[r * LDT + sc8] = bv[i];
            }
        }
    }

    const int p = n0 / EMBED;                 // 0=q,1=k,2=v (block-uniform)
    const int ncol0 = n0 + wn;                // 64-aligned
    const int h = (ncol0 % EMBED) / HDIM;     // wave-uniform head
    const int mrow0 = m0 + wm;
    const int b = mrow0 >> 11;                // 64-strips never cross batch
    const int s0 = mrow0 & (SEQ - 1);

    if (p < 2) {
        u16* dst = (p == 0) ? Qb : Kb;
        const float mul = (p == 0) ? SCALING : 1.0f;
        #pragma unroll
        for (int j = 0; j < 4; ++j) {
            int n = ncol0 + j * 16 + c;
            int d = j * 16 + c;
            float bval = bias[n];
            #pragma unroll
            for (int i = 0; i < 4; ++i) {
                #pragma unroll
                for (int r = 0; r < 4; ++r) {
                    int s = s0 + i * 16 + q * 4 + r;
                    float v = (acc[i][j][r] + bval) * mul;
                    dst[(((size_t)(b * NHEADS + h)) * SEQ + s) * HDIM + d] = f2b(v);
                }
            }
        }
    } else {
        // V: transpose 64x64 wave tile through reused LDS, write V^T rows.
        __syncthreads();                      // all MFMA LDS reads done
        u16* T = smem + w * (64 * LT);        // wave-private scratch
        #pragma unroll
        for (int j = 0; j < 4; ++j) {
            int n = ncol0 + j * 16 + c;
            float bval = bias[n];
            #pragma unroll
            for (int i = 0; i < 4; ++i) {
                uint2 pr;
                pr.x = pk2(acc[i][j][0] + bval, acc[i][j][1] + bval);
                pr.y = pk2(acc[i][j][2] + bval, acc[i][j][3] + bval);
                *(uint2*)&T[(j * 16 + c) * LT + i * 16 + q * 4] = pr;
            }
        }
        // wave-private region: in-wave DS ordering suffices, no barrier
        const size_t vtbase = ((size_t)(b * NHEADS + h)) * HDIM * SEQ + s0;
        #pragma unroll
        for (int ii = 0; ii < 8; ++ii) {
            int d = (l >> 3) + 8 * ii;
            int sch = (l & 7) * 8;
            uint4 vv = *(const uint4*)&T[d * LT + sch];
            *(uint4*)&VT[vtbase + (size_t)d * SEQ + sch] = vv;
        }
    }
}

// ---------------------------------------------------------------------------
// Flash attention, S^T formulation, K-range split in two (blockIdx.z).
// Single-buffered K/V LDS + register prefetch; Q frags loaded direct from
// global; per-wave P strip in LDS. Writes UNNORMALIZED partial O + (m,l).
// LDS = 27.6 KB -> 5 blocks/CU; grid 1536 blocks -> ~20 waves/CU.
// ---------------------------------------------------------------------------
__global__ __launch_bounds__(256)
void attn_kernel(const u16* __restrict__ Qb, const u16* __restrict__ Kb,
                 const u16* __restrict__ VT,
                 float* __restrict__ PO, float* __restrict__ PML)
{
    __shared__ __align__(16) u16 Ks[64 * LQ];
    __shared__ __align__(16) u16 Vs[64 * LQ];     // V^T tile [d][t]
    __shared__ __align__(16) u16 Ps[4][16 * LQ];  // wave-private P strips

    const int qt = blockIdx.x;
    const int bh = blockIdx.y;
    const int z  = blockIdx.z;
    const int tid = threadIdx.x;
    const int w = tid >> 6, l = tid & 63;
    const int c = l & 15, q = l >> 4;
    const int lr = tid >> 3, ld = (tid & 7) * 8;

    const u16* qg = Qb + ((size_t)bh * SEQ + qt * 64) * HDIM;
    const u16* kg = Kb + ((size_t)bh * SEQ + z * (SEQ / 2)) * HDIM;
    const u16* vg = VT + ((size_t)bh * HDIM) * SEQ + z * (SEQ / 2);

    // Q^T B-fragments straight from global (once)
    bf16x8 bq0 = *(const bf16x8*)&qg[(w * 16 + c) * HDIM + q * 8];
    bf16x8 bq1 = *(const bf16x8*)&qg[(w * 16 + c) * HDIM + 32 + q * 8];

    // prologue prefetch of tile 0
    uint4 kv[2], vv[2];
    #pragma unroll
    for (int i = 0; i < 2; ++i) {
        int r = lr + i * 32;
        kv[i] = *(const uint4*)&kg[(size_t)r * HDIM + ld];
        vv[i] = *(const uint4*)&vg[(size_t)r * SEQ + ld];
    }

    u16* ps = Ps[w];
    f32x4 o[4] = {};
    float mrow = -1e30f, lrow = 0.f;

    const int NT = (SEQ / 2) / 64;   // 16
    for (int kt = 0; kt < NT; ++kt) {
        if (kt) __syncthreads();     // prev iteration's readers done
        #pragma unroll
        for (int i = 0; i < 2; ++i) {
            int r = lr + i * 32;
            *(uint4*)&Ks[r * LQ + ld] = kv[i];
            *(uint4*)&Vs[r * LQ + ld] = vv[i];
        }
        __syncthreads();
        if (kt + 1 < NT) {           // prefetch next tile into registers
            #pragma unroll
            for (int i = 0; i < 2; ++i) {
                int r = lr + i * 32;
                kv[i] = *(const uint4*)&kg[(size_t)((kt + 1) * 64 + r) * HDIM + ld];
                vv[i] = *(const uint4*)&vg[(size_t)r * SEQ + (kt + 1) * 64 + ld];
            }
        }

        // S^T[key][qrow]: A = K, B = Q^T
        f32x4 sc[4];
        #pragma unroll
        for (int kb = 0; kb < 4; ++kb) {
            bf16x8 ak0 = *(const bf16x8*)&Ks[(kb * 16 + c) * LQ + q * 8];
            bf16x8 ak1 = *(const bf16x8*)&Ks[(kb * 16 + c) * LQ + 32 + q * 8];
            f32x4 zz = {};
            zz = mfma16(ak0, bq0, zz);
            sc[kb] = mfma16(ak1, bq1, zz);
        }

        // online softmax for qrow c: 16 in-lane values + 2 cross-q shfls
        float t0 = fmaxf(fmaxf(sc[0][0], sc[0][1]), fmaxf(sc[0][2], sc[0][3]));
        float t1 = fmaxf(fmaxf(sc[1][0], sc[1][1]), fmaxf(sc[1][2], sc[1][3]));
        float t2 = fmaxf(fmaxf(sc[2][0], sc[2][1]), fmaxf(sc[2][2], sc[2][3]));
        float t3 = fmaxf(fmaxf(sc[3][0], sc[3][1]), fmaxf(sc[3][2], sc[3][3]));
        float tm = fmaxf(fmaxf(t0, t1), fmaxf(t2, t3));
        tm = fmaxf(tm, __shfl_xor(tm, 16));
        tm = fmaxf(tm, __shfl_xor(tm, 32));
        float mnew = fmaxf(mrow, tm);
        float corr = __expf(mrow - mnew);
        float rs = 0.f;
        #pragma unroll
        for (int kb = 0; kb < 4; ++kb)
            #pragma unroll
            for (int r = 0; r < 4; ++r) {
                float p = __expf(sc[kb][r] - mnew);
                sc[kb][r] = p;
                rs += p;
            }
        rs += __shfl_xor(rs, 16);
        rs += __shfl_xor(rs, 32);
        lrow = lrow * corr + rs;
        mrow = mnew;

        // P strip [qrow c][key], 4 consecutive keys per b64 write
        #pragma unroll
        for (int kb = 0; kb < 4; ++kb) {
            uint2 pr;
            pr.x = pk2(sc[kb][0], sc[kb][1]);
            pr.y = pk2(sc[kb][2], sc[kb][3]);
            *(uint2*)&ps[c * LQ + kb * 16 + q * 4] = pr;
        }
        bf16x8 bp0 = *(const bf16x8*)&ps[c * LQ + q * 8];
        bf16x8 bp1 = *(const bf16x8*)&ps[c * LQ + 32 + q * 8];

        // O^T = corr*O^T + V^T·P^T
        #pragma unroll
        for (int db = 0; db < 4; ++db) {
            bf16x8 av0 = *(const bf16x8*)&Vs[(db * 16 + c) * LQ + q * 8];
            bf16x8 av1 = *(const bf16x8*)&Vs[(db * 16 + c) * LQ + 32 + q * 8];
            f32x4 t = o[db] * corr;
            t = mfma16(av0, bp0, t);
            t = mfma16(av1, bp1, t);
            o[db] = t;
        }
    }

    // epilogue: unnormalized partial O + (m,l)
    size_t rowg = ((size_t)(z * BHTOT + bh)) * SEQ + qt * 64 + w * 16 + c;
    #pragma unroll
    for (int db = 0; db < 4; ++db)
        *(f32x4*)&PO[rowg * HDIM + db * 16 + q * 4] = o[db];
    if (q == 0) {
        PML[rowg * 2 + 0] = mrow;
        PML[rowg * 2 + 1] = lrow;
    }
}

// ---------------------------------------------------------------------------
// Merge the two K-half partials -> AO bf16 [token][EMBED]
// ---------------------------------------------------------------------------
__global__ __launch_bounds__(256)
void merge_kernel(const float* __restrict__ PO, const float* __restrict__ PML,
                  u16* __restrict__ AO)
{
    int t = blockIdx.x * 256 + threadIdx.x;   // 24*2048*8 = 393216
    int dc = t & 7;
    int s  = (t >> 3) & (SEQ - 1);
    int bh = t >> 14;
    size_t row1 = (size_t)bh * SEQ + s;
    size_t row2 = row1 + (size_t)BHTOT * SEQ;
    float m1 = PML[row1 * 2], l1 = PML[row1 * 2 + 1];
    float m2 = PML[row2 * 2], l2 = PML[row2 * 2 + 1];
    float m = fmaxf(m1, m2);
    float a1 = __expf(m1 - m), a2 = __expf(m2 - m);
    float inv = 1.0f / (a1 * l1 + a2 * l2);
    a1 *= inv; a2 *= inv;
    const float* o1 = &PO[row1 * HDIM + dc * 8];
    const float* o2 = &PO[row2 * HDIM + dc * 8];
    float4 x1 = *(const float4*)o1, y1 = *(const float4*)(o1 + 4);
    float4 x2 = *(const float4*)o2, y2 = *(const float4*)(o2 + 4);
    uint4 o;
    o.x = pk2(x1.x * a1 + x2.x * a2, x1.y * a1 + x2.y * a2);
    o.y = pk2(x1.z * a1 + x2.z * a2, x1.w * a1 + x2.w * a2);
    o.z = pk2(y1.x * a1 + y2.x * a2, y1.y * a1 + y2.y * a2);
    o.w = pk2(y1.z * a1 + y2.z * a2, y1.w * a1 + y2.w * a2);
    int b = bh / NHEADS, h = bh % NHEADS;
    *(uint4*)&AO[((size_t)(b * SEQ + s)) * EMBED + h * HDIM + dc * 8] = o;
}

// ---------------------------------------------------------------------------
// Output projection, 128x64 tile, double-buffered.
// ---------------------------------------------------------------------------
__global__ __launch_bounds__(256)
void out_gemm(const u16* __restrict__ A, const u16* __restrict__ W,
              const float* __restrict__ bias, float* __restrict__ out)
{
    __shared__ __align__(16) u16 As[2][128 * LDT];
    __shared__ __align__(16) u16 Bs[2][64 * LDT];
    const int m0 = blockIdx.x * 128;
    const int n0 = blockIdx.y * 64;
    const int tid = threadIdx.x;
    const int w = tid >> 6, l = tid & 63;
    const int c = l & 15, q = l >> 4;
    const int wm = w * 32;
    const int srow = tid >> 2, sc8 = (tid & 3) * 8;

    #pragma unroll
    for (int i = 0; i < 2; ++i) {
        int r = srow + i * 64;
        *(uint4*)&As[0][r * LDT + sc8] = *(const uint4*)&A[(size_t)(m0 + r) * EMBED + sc8];
    }
    *(uint4*)&Bs[0][srow * LDT + sc8] = *(const uint4*)&W[(size_t)(n0 + srow) * EMBED + sc8];

    f32x4 acc[2][4] = {};
    const int NK = EMBED / 32;

    #pragma unroll 2
    for (int kt = 0; kt < NK; ++kt) {
        const int cur = kt & 1;
        uint4 av[2], bv;
        if (kt + 1 < NK) {
            int k0 = (kt + 1) * 32;
            #pragma unroll
            for (int i = 0; i < 2; ++i) {
                int r = srow + i * 64;
                av[i] = *(const uint4*)&A[(size_t)(m0 + r) * EMBED + k0 + sc8];
            }
            bv = *(const uint4*)&W[(size_t)(n0 + srow) * EMBED + k0 + sc8];
        }
        __syncthreads();
        bf16x8 af[2], bf_[4];
        #pragma unroll
        for (int i = 0; i < 2; ++i)
            af[i] = *(const bf16x8*)&As[cur][(wm + i * 16 + c) * LDT + q * 8];
        #pragma unroll
        for (int j = 0; j < 4; ++j)
            bf_[j] = *(const bf16x8*)&Bs[cur][(j * 16 + c) * LDT + q * 8];
        #pragma unroll
        for (int i = 0; i < 2; ++i)
            #pragma unroll
            for (int j = 0; j < 4; ++j)
                acc[i][j] = mfma16(af[i], bf_[j], acc[i][j]);
        if (kt + 1 < NK) {
            #pragma unroll
            for (int i = 0; i < 2; ++i) {
                int r = srow + i * 64;
                *(uint4*)&As[cur ^ 1][r * LDT + sc8] = av[i];
            }
            *(uint4*)&Bs[cur ^ 1][srow * LDT + sc8] = bv;
        }
    }

    #pragma unroll
    for (int j = 0; j < 4; ++j) {
        int n = n0 + j * 16 + c;
        float bval = bias[n];
        #pragma unroll
        for (int i = 0; i < 2; ++i) {
            #pragma unroll
            for (int r = 0; r < 4; ++r) {
                int m = m0 + wm + i * 16 + q * 4 + r;
                out[(size_t)m * EMBED + n] = acc[i][j][r] + bval;
            }
        }
    }
}

// ---------------------------------------------------------------------------
extern "C" void kernel_launch(void* const* d_in, const int* in_sizes, int n_in,
                              void* d_out, int out_size, void* d_ws, size_t ws_size,
                              hipStream_t stream)
{
    const float* x    = (const float*)d_in[0];
    const float* wqkv = (const float*)d_in[1];
    const float* bqkv = (const float*)d_in[2];
    const float* wout = (const float*)d_in[3];
    const float* bout = (const float*)d_in[4];
    float* out = (float*)d_out;

    const int nwq = QKV_N * EMBED;        // 1,769,472
    const int nwo = EMBED * EMBED;        //   589,824
    const size_t per = (size_t)NBATCH * NHEADS * SEQ * HDIM;  // 3,145,728

    u16* wqkvb = (u16*)d_ws;
    u16* woutb = wqkvb + nwq;
    u16* Qb    = woutb + nwo;
    u16* Kb    = Qb + per;
    u16* VT    = Kb + per;
    float* PO  = (float*)(VT + per);              // 2*24*2048*64 f32
    float* PML = PO + 2 * (size_t)BHTOT * SEQ * HDIM;  // 2*24*2048*2 f32
    u16* AO    = Qb;   // Qb is dead after attn; reuse for merged AO

    cast_w<<<(nwq + nwo) / 1024, 256, 0, stream>>>(wqkv, wqkvb, nwq, wout, woutb, nwo);

    dim3 g1(NTOK / 128, QKV_N / 128);     // (32, 18)
    qkv_gemm<<<g1, 256, 0, stream>>>(x, wqkvb, bqkv, Qb, Kb, VT);

    dim3 g2(SEQ / 64, BHTOT, 2);          // (32, 24, 2) = 1536 blocks
    attn_kernel<<<g2, 256, 0, stream>>>(Qb, Kb, VT, PO, PML);

    merge_kernel<<<(BHTOT * SEQ * 8) / 256, 256, 0, stream>>>(PO, PML, AO);

    dim3 g3(NTOK / 128, EMBED / 64);      // (32, 12)
    out_gemm<<<g3, 256, 0, stream>>>(AO, woutb, bout, out);
}